// Round 4
// baseline (5991.668 us; speedup 1.0000x reference)
//
#include <hip/hip_runtime.h>
#include <hip/hip_fp16.h>

#define H 161
#define G4 644            // 4*H gates
#define BB 32             // batch
#define TT 1000           // time
#define M_TOT (BB*TT)     // 32000 rows
#define KP2 84            // half2 pairs per gate row (K padded to 168)

typedef _Float16 h2_t __attribute__((ext_vector_type(2)));

__device__ __forceinline__ h2_t bc_h2(unsigned int u) {
    return __builtin_bit_cast(h2_t, u);
}

__device__ __forceinline__ float dot2f(h2_t a, h2_t b, float c) {
#if __has_builtin(__builtin_amdgcn_fdot2)
    return __builtin_amdgcn_fdot2(a, b, c, false);
#else
    return c + (float)a[0] * (float)b[0] + (float)a[1] * (float)b[1];
#endif
}

__device__ __forceinline__ float sigm_f(float x) {
    return 1.0f / (1.0f + __expf(-x));
}
__device__ __forceinline__ float tanh_f(float x) {
    return 1.0f - 2.0f / (__expf(2.0f * x) + 1.0f);
}

// Barrier draining only LDS (lgkmcnt), not vmcnt: hcat stores and pre
// prefetch loads stay in flight across step boundaries.
__device__ __forceinline__ void bar_lds() {
    __builtin_amdgcn_sched_barrier(0);
    asm volatile("s_waitcnt lgkmcnt(0)" ::: "memory");
    __builtin_amdgcn_s_barrier();
    __builtin_amdgcn_sched_barrier(0);
}

// ---------------------------------------------------------------------------
// pre_gemm: pre[d][m][col*4+gate] = sum_k A[m][k]*wih_d[gate*H+col][k] + biases
// (col*4+gate layout: lstm_scan lane `col` loads its 4 gate pre-values with
// one aligned 8-byte read)
// ---------------------------------------------------------------------------
__global__ __launch_bounds__(256) void pre_gemm(
    const float* __restrict__ A,
    const float* __restrict__ wf, const float* __restrict__ wb,
    const float* __restrict__ bif, const float* __restrict__ bhf,
    const float* __restrict__ bib, const float* __restrict__ bhb,
    __half* __restrict__ pre)
{
    const int BM = 64, BN = 64, BK = 16;
    int m0 = blockIdx.x * BM;
    int n0 = blockIdx.y * BN;
    __shared__ float As[BK][BM + 1];
    __shared__ float Bs[BK][BN + 1];
    int tid = threadIdx.x;
    int tx = tid & 15, ty = tid >> 4;
    float acc[4][4] = {};

    for (int k0 = 0; k0 < H; k0 += BK) {
        #pragma unroll
        for (int l = 0; l < (BM * BK) / 256; ++l) {
            int e = tid + l * 256;
            int mm = e / BK, kk = e % BK;
            int k = k0 + kk;
            As[kk][mm] = (k < H) ? A[(size_t)(m0 + mm) * H + k] : 0.f;
        }
        #pragma unroll
        for (int l = 0; l < (BN * BK) / 256; ++l) {
            int e = tid + l * 256;
            int nn = e / BK, kk = e % BK;
            int n = n0 + nn, k = k0 + kk;
            float v = 0.f;
            if (k < H && n < 2 * G4)
                v = (n < G4) ? wf[(size_t)n * H + k] : wb[(size_t)(n - G4) * H + k];
            Bs[kk][nn] = v;
        }
        __syncthreads();
        #pragma unroll
        for (int kk = 0; kk < BK; ++kk) {
            float a4[4], b4[4];
            #pragma unroll
            for (int i = 0; i < 4; ++i) a4[i] = As[kk][ty + 16 * i];
            #pragma unroll
            for (int j = 0; j < 4; ++j) b4[j] = Bs[kk][tx + 16 * j];
            #pragma unroll
            for (int i = 0; i < 4; ++i)
                #pragma unroll
                for (int j = 0; j < 4; ++j) acc[i][j] += a4[i] * b4[j];
        }
        __syncthreads();
    }

    #pragma unroll
    for (int i = 0; i < 4; ++i) {
        int m = m0 + ty + 16 * i;
        #pragma unroll
        for (int j = 0; j < 4; ++j) {
            int n = n0 + tx + 16 * j;
            if (n < 2 * G4) {
                int d = (n >= G4) ? 1 : 0;
                int g = n - d * G4;
                int gate = g / H;
                int col = g - gate * H;
                float bias = d ? (bib[g] + bhb[g]) : (bif[g] + bhf[g]);
                pre[((size_t)d * M_TOT + m) * G4 + col * 4 + gate] =
                    __float2half(acc[i][j] + bias);
            }
        }
    }
}

// ---------------------------------------------------------------------------
// lstm_scan: one block per (batch, direction), 192 threads = 3 waves =
// 1 wave per SIMD -> full 512-VGPR budget per wave (the 704-thread variants
// were capped at 170 total regs/wave and spilled the weight array).
// Lane `col` (< 161) owns ALL FOUR gate rows of its column: w[4][84] half2
// = 336 VGPRs, all dots + activations + c update lane-local. No gate_sh
// round-trip, no cross-lane reduce, ONE barrier per step. h double-buffered
// in LDS (uniform-address broadcast reads). pre loaded as one aligned uint2
// per lane per step, prefetched 2 steps deep across the vmcnt-free barrier.
// ---------------------------------------------------------------------------
__global__ __launch_bounds__(192, 1) void lstm_scan(
    const __half* __restrict__ pre,      // [2][M_TOT][G4], col*4+gate layout
    const float* __restrict__ whh_f,
    const float* __restrict__ whh_b,
    float* __restrict__ hcat)            // [M_TOT][2*H]
{
    const int b = blockIdx.x;            // 0..31
    const int d = blockIdx.y;            // 0,1
    const int tid = threadIdx.x;
    const float* whh = d ? whh_b : whh_f;

    __shared__ __align__(16) unsigned int h_sh[2][96];  // 2 x 192 halfs (168 used)

    const int col = (tid < H) ? tid : (H - 1);   // clamp lanes 161..191
    const bool writer = (tid < H);

    // All 4 gate rows of this column, packed half2, K padded to 168.
    unsigned int w[4 * KP2];
    #pragma unroll
    for (int g = 0; g < 4; ++g) {
        const float* row = whh + (size_t)(g * H + col) * H;
        #pragma unroll
        for (int i = 0; i < KP2; ++i) {
            int k = 2 * i;
            float w0 = (k < H) ? row[k] : 0.f;
            float w1 = (k + 1 < H) ? row[k + 1] : 0.f;
            h2_t v; v[0] = (_Float16)w0; v[1] = (_Float16)w1;
            w[g * KP2 + i] = __builtin_bit_cast(unsigned int, v);
        }
    }
    if (tid < 96) { h_sh[0][tid] = 0u; h_sh[1][tid] = 0u; }

    float c = 0.f;
    const __half* pb = pre + ((size_t)d * M_TOT + (size_t)b * TT) * G4
                           + (size_t)col * 4;

    // Load the lane's 4 pre halfs for logical step tt_ (clamped; stale
    // epilogue prefetches are never consumed). 8B-aligned coalesced read.
    #define LDP(tt_) ({ int tc_ = ((tt_) < TT) ? (tt_) : (TT - 1);          \
                        int t_  = d ? (TT - 1 - tc_) : tc_;                 \
                        *(const uint2*)(pb + (size_t)t_ * G4); })

    uint2 p0 = LDP(0), p1 = LDP(1);
    __syncthreads();

    #define STEP(TTT, PJ, BUF) {                                            \
        int t = d ? (TT - 1 - (TTT)) : (TTT);                               \
        h2_t s01 = bc_h2(PJ.x), s23 = bc_h2(PJ.y);                          \
        float a0 = (float)s01[0], a1 = (float)s01[1];                       \
        float a2 = (float)s23[0], a3 = (float)s23[1];                       \
        PJ = LDP((TTT) + 2);          /* issue 2-steps-ahead prefetch */    \
        const uint4* h4 = (const uint4*)(h_sh[BUF]);                        \
        _Pragma("unroll")                                                   \
        for (int i = 0; i < 21; ++i) {                                      \
            uint4 hh = h4[i];                                               \
            h2_t hx = bc_h2(hh.x), hy = bc_h2(hh.y);                        \
            h2_t hz = bc_h2(hh.z), hw = bc_h2(hh.w);                        \
            a0 = dot2f(bc_h2(w[0*KP2+4*i+0]), hx, a0);                      \
            a0 = dot2f(bc_h2(w[0*KP2+4*i+1]), hy, a0);                      \
            a0 = dot2f(bc_h2(w[0*KP2+4*i+2]), hz, a0);                      \
            a0 = dot2f(bc_h2(w[0*KP2+4*i+3]), hw, a0);                      \
            a1 = dot2f(bc_h2(w[1*KP2+4*i+0]), hx, a1);                      \
            a1 = dot2f(bc_h2(w[1*KP2+4*i+1]), hy, a1);                      \
            a1 = dot2f(bc_h2(w[1*KP2+4*i+2]), hz, a1);                      \
            a1 = dot2f(bc_h2(w[1*KP2+4*i+3]), hw, a1);                      \
            a2 = dot2f(bc_h2(w[2*KP2+4*i+0]), hx, a2);                      \
            a2 = dot2f(bc_h2(w[2*KP2+4*i+1]), hy, a2);                      \
            a2 = dot2f(bc_h2(w[2*KP2+4*i+2]), hz, a2);                      \
            a2 = dot2f(bc_h2(w[2*KP2+4*i+3]), hw, a2);                      \
            a3 = dot2f(bc_h2(w[3*KP2+4*i+0]), hx, a3);                      \
            a3 = dot2f(bc_h2(w[3*KP2+4*i+1]), hy, a3);                      \
            a3 = dot2f(bc_h2(w[3*KP2+4*i+2]), hz, a3);                      \
            a3 = dot2f(bc_h2(w[3*KP2+4*i+3]), hw, a3);                      \
        }                                                                   \
        float ig = sigm_f(a0);                                              \
        float fg = sigm_f(a1);                                              \
        float gg = tanh_f(a2);                                              \
        float og = sigm_f(a3);                                              \
        c = fg * c + ig * gg;                                               \
        float hval = og * tanh_f(c);                                        \
        if (writer) {                                                       \
            hcat[((size_t)b * TT + t) * (2 * H) + (size_t)d * H + col] = hval; \
            ((__half*)h_sh[(BUF) ^ 1])[col] = __float2half(hval);           \
        }                                                                   \
        bar_lds();                                                          \
    }

    for (int base = 0; base < TT; base += 2) {
        STEP(base,     p0, 0)
        STEP(base + 1, p1, 1)
    }
    #undef STEP
    #undef LDP
}

// ---------------------------------------------------------------------------
// lin_gemm: out[m][n] = relu?(sum_k hcat[m][k]*W[n][k] + bl[n]) + res[m][n]
// ---------------------------------------------------------------------------
__global__ __launch_bounds__(256) void lin_gemm(
    const float* __restrict__ A,     // [M_TOT][2H]
    const float* __restrict__ W,     // [H][2H]
    const float* __restrict__ bl,    // [H]
    const float* __restrict__ res,   // [M_TOT][H]
    float* __restrict__ out,         // [M_TOT][H]
    int relu)
{
    const int BM = 64, BN = 64, BK = 16;
    const int K = 2 * H;
    int m0 = blockIdx.x * BM;
    int n0 = blockIdx.y * BN;
    __shared__ float As[BK][BM + 1];
    __shared__ float Bs[BK][BN + 1];
    int tid = threadIdx.x;
    int tx = tid & 15, ty = tid >> 4;
    float acc[4][4] = {};

    for (int k0 = 0; k0 < K; k0 += BK) {
        #pragma unroll
        for (int l = 0; l < (BM * BK) / 256; ++l) {
            int e = tid + l * 256;
            int mm = e / BK, kk = e % BK;
            int k = k0 + kk;
            As[kk][mm] = (k < K) ? A[(size_t)(m0 + mm) * K + k] : 0.f;
        }
        #pragma unroll
        for (int l = 0; l < (BN * BK) / 256; ++l) {
            int e = tid + l * 256;
            int nn = e / BK, kk = e % BK;
            int n = n0 + nn, k = k0 + kk;
            Bs[kk][nn] = (k < K && n < H) ? W[(size_t)n * K + k] : 0.f;
        }
        __syncthreads();
        #pragma unroll
        for (int kk = 0; kk < BK; ++kk) {
            float a4[4], b4[4];
            #pragma unroll
            for (int i = 0; i < 4; ++i) a4[i] = As[kk][ty + 16 * i];
            #pragma unroll
            for (int j = 0; j < 4; ++j) b4[j] = Bs[kk][tx + 16 * j];
            #pragma unroll
            for (int i = 0; i < 4; ++i)
                #pragma unroll
                for (int j = 0; j < 4; ++j) acc[i][j] += a4[i] * b4[j];
        }
        __syncthreads();
    }

    #pragma unroll
    for (int i = 0; i < 4; ++i) {
        int m = m0 + ty + 16 * i;
        #pragma unroll
        for (int j = 0; j < 4; ++j) {
            int n = n0 + tx + 16 * j;
            if (n < H) {
                float v = acc[i][j] + bl[n];
                if (relu) v = fmaxf(v, 0.f);
                v += res[(size_t)m * H + n];
                out[(size_t)m * H + n] = v;
            }
        }
    }
}

extern "C" void kernel_launch(void* const* d_in, const int* in_sizes, int n_in,
                              void* d_out, int out_size, void* d_ws, size_t ws_size,
                              hipStream_t stream) {
    const float* x = (const float*)d_in[0];

    char* ws = (char*)d_ws;
    __half* pre = (__half*)ws;                                   // 82.4 MB
    float* hcat = (float*)(ws + (size_t)2 * M_TOT * G4 * sizeof(__half));
    float* bufA = hcat + (size_t)M_TOT * 2 * H;
    float* bufB = bufA + (size_t)M_TOT * H;

    const float* cur = x;
    float* outs[3] = {bufA, bufB, (float*)d_out};

    for (int l = 0; l < 3; ++l) {
        const float* const* p = (const float* const*)(d_in + 1 + 10 * l);
        dim3 g1(M_TOT / 64, 21);
        pre_gemm<<<g1, 256, 0, stream>>>(cur, p[0], p[4], p[2], p[3], p[6], p[7], pre);
        lstm_scan<<<dim3(32, 2), 192, 0, stream>>>(pre, p[1], p[5], hcat);
        dim3 g2(M_TOT / 64, 3);
        lin_gemm<<<g2, 256, 0, stream>>>(hcat, p[8], p[9], cur, outs[l], (l < 2) ? 1 : 0);
        cur = outs[l];
    }
}

// Round 5
// 5325.963 us; speedup vs baseline: 1.1250x; 1.1250x over previous
//
#include <hip/hip_runtime.h>
#include <hip/hip_fp16.h>

#define H 161
#define H2 322            // 2*H = i/f row block, also pair offset
#define G4 644            // 4*H gates
#define BB 32             // batch
#define TT 1000           // time
#define M_TOT (BB*TT)     // 32000 rows
#define KP2 84            // half2 pairs per gate row (K padded to 168)

typedef _Float16 h2_t __attribute__((ext_vector_type(2)));

__device__ __forceinline__ h2_t bc_h2(unsigned int u) {
    return __builtin_bit_cast(h2_t, u);
}

__device__ __forceinline__ float dot2f(h2_t a, h2_t b, float c) {
#if __has_builtin(__builtin_amdgcn_fdot2)
    return __builtin_amdgcn_fdot2(a, b, c, false);
#else
    return c + (float)a[0] * (float)b[0] + (float)a[1] * (float)b[1];
#endif
}

__device__ __forceinline__ float sigm_f(float x) {
    return 1.0f / (1.0f + __expf(-x));
}
__device__ __forceinline__ float tanh_f(float x) {
    return 1.0f - 2.0f / (__expf(2.0f * x) + 1.0f);
}

// Barrier draining only LDS (lgkmcnt), not vmcnt: hcat stores and pre
// prefetch loads stay in flight across step boundaries.
__device__ __forceinline__ void bar_lds() {
    __builtin_amdgcn_sched_barrier(0);
    asm volatile("s_waitcnt lgkmcnt(0)" ::: "memory");
    __builtin_amdgcn_s_barrier();
    __builtin_amdgcn_sched_barrier(0);
}

// ---------------------------------------------------------------------------
// pre_gemm: same GEMM as before; epilogue writes the PAIR layout:
// pre2[d][m][L] = uint packing halfs (pre[gate L], pre[gate L+322]), L<322.
// Gate index g is gate-major (g = gtype*H + hid): g<322 -> slot 0 of L=g,
// g>=322 -> slot 1 of L=g-322. lstm_scan lane L then loads its two pre
// values with ONE coalesced 4-byte read.
// ---------------------------------------------------------------------------
__global__ __launch_bounds__(256) void pre_gemm(
    const float* __restrict__ A,
    const float* __restrict__ wf, const float* __restrict__ wb,
    const float* __restrict__ bif, const float* __restrict__ bhf,
    const float* __restrict__ bib, const float* __restrict__ bhb,
    __half* __restrict__ pre2)           // [2][M_TOT][322] uint pairs, as half*
{
    const int BM = 64, BN = 64, BK = 16;
    int m0 = blockIdx.x * BM;
    int n0 = blockIdx.y * BN;
    __shared__ float As[BK][BM + 1];
    __shared__ float Bs[BK][BN + 1];
    int tid = threadIdx.x;
    int tx = tid & 15, ty = tid >> 4;
    float acc[4][4] = {};

    for (int k0 = 0; k0 < H; k0 += BK) {
        #pragma unroll
        for (int l = 0; l < (BM * BK) / 256; ++l) {
            int e = tid + l * 256;
            int mm = e / BK, kk = e % BK;
            int k = k0 + kk;
            As[kk][mm] = (k < H) ? A[(size_t)(m0 + mm) * H + k] : 0.f;
        }
        #pragma unroll
        for (int l = 0; l < (BN * BK) / 256; ++l) {
            int e = tid + l * 256;
            int nn = e / BK, kk = e % BK;
            int n = n0 + nn, k = k0 + kk;
            float v = 0.f;
            if (k < H && n < 2 * G4)
                v = (n < G4) ? wf[(size_t)n * H + k] : wb[(size_t)(n - G4) * H + k];
            Bs[kk][nn] = v;
        }
        __syncthreads();
        #pragma unroll
        for (int kk = 0; kk < BK; ++kk) {
            float a4[4], b4[4];
            #pragma unroll
            for (int i = 0; i < 4; ++i) a4[i] = As[kk][ty + 16 * i];
            #pragma unroll
            for (int j = 0; j < 4; ++j) b4[j] = Bs[kk][tx + 16 * j];
            #pragma unroll
            for (int i = 0; i < 4; ++i)
                #pragma unroll
                for (int j = 0; j < 4; ++j) acc[i][j] += a4[i] * b4[j];
        }
        __syncthreads();
    }

    #pragma unroll
    for (int i = 0; i < 4; ++i) {
        int m = m0 + ty + 16 * i;
        #pragma unroll
        for (int j = 0; j < 4; ++j) {
            int n = n0 + tx + 16 * j;
            if (n < 2 * G4) {
                int d = (n >= G4) ? 1 : 0;
                int g = n - d * G4;                  // gate-major 0..643
                int L    = (g < H2) ? g : (g - H2);  // pair lane
                int slot = (g < H2) ? 0 : 1;
                float bias = d ? (bib[g] + bhb[g]) : (bif[g] + bhf[g]);
                pre2[(((size_t)d * M_TOT + m) * H2 + L) * 2 + slot] =
                    __float2half(acc[i][j] + bias);
            }
        }
    }
}

// ---------------------------------------------------------------------------
// lstm_scan v5: one block per (batch, direction), 384 threads = 6 waves.
// Lane L < 322 owns TWO gate rows: (L, L+322) = (i_L, g_L) for L<161 and
// (f_{L-161}, o_{L-161}) otherwise. Weights = 168 packed-half2 arch VGPRs
// (fits the 256 arch cap cleanly; the 704-thread variants were forced into
// AGPR copies, the 192-thread one into scratch spills -- both measured).
//
// h broadcast via SGPRs: lane j<42 holds h pairs (2j, 2j+1) from ONE
// ds_read_b64; 84 static v_readlane's feed v_dot2's scalar operand.
// LDS h-broadcast traffic (the measured R1 floor, ~1850 cyc/step) -> ~0.
//
// Exchange: only f/o lanes publish (float2 gsh[161]); the i/g lane of each
// hid already holds ig, gg in registers and does the c,h update.
// Two lgkm-only barriers per step; pre prefetched 2 deep across them.
// ---------------------------------------------------------------------------
__global__ __launch_bounds__(384, 1) void lstm_scan(
    const unsigned int* __restrict__ pre2,   // [2][M_TOT][322] packed pairs
    const float* __restrict__ whh_f,
    const float* __restrict__ whh_b,
    float* __restrict__ hcat)                // [M_TOT][2*H]
{
    const int b = blockIdx.x;            // 0..31
    const int d = blockIdx.y;            // 0,1
    const int tid = threadIdx.x;
    const float* whh = d ? whh_b : whh_f;

    __shared__ __align__(8) unsigned int h_sh[KP2];   // 168 halfs as 84 pairs
    __shared__ float2 gsh[H];                          // (fg, og) per hid

    const bool active = tid < H2;
    const int L = active ? tid : (H2 - 1);            // clamp lanes 322..383
    const bool low = (L < H);                          // i/g lane (owns hid L)

    // Two weight rows, packed half2, K padded to 168. 168 arch VGPRs.
    unsigned int w0[KP2], w1[KP2];
    {
        const float* r0 = whh + (size_t)L * H;         // rows 0..321 = i,f
        const float* r1 = whh + (size_t)(L + H2) * H;  // rows 322..643 = g,o
        #pragma unroll
        for (int i = 0; i < KP2; ++i) {
            int k = 2 * i;
            float a0 = (k < H) ? r0[k] : 0.f;
            float a1 = (k + 1 < H) ? r0[k + 1] : 0.f;
            float b0 = (k < H) ? r1[k] : 0.f;
            float b1 = (k + 1 < H) ? r1[k + 1] : 0.f;
            h2_t v0; v0[0] = (_Float16)a0; v0[1] = (_Float16)a1;
            h2_t v1; v1[0] = (_Float16)b0; v1[1] = (_Float16)b1;
            w0[i] = __builtin_bit_cast(unsigned int, v0);
            w1[i] = __builtin_bit_cast(unsigned int, v1);
        }
    }
    if (tid < KP2) h_sh[tid] = 0u;

    float c = 0.f;
    const unsigned int* pb = pre2 + ((size_t)d * M_TOT + (size_t)b * TT) * H2 + L;

    #define LDP(tt_) ({ int tc_ = ((tt_) < TT) ? (tt_) : (TT - 1);          \
                        int t_  = d ? (TT - 1 - tc_) : tc_;                 \
                        pb[(size_t)t_ * H2]; })

    unsigned int p0 = LDP(0), p1 = LDP(1);
    __syncthreads();

    const int lane = tid & 63;
    const int hj = (lane < 42) ? lane : 41;            // h-pair holder index

    #define STEP(TTT, PJ) {                                                 \
        int t = d ? (TT - 1 - (TTT)) : (TTT);                               \
        h2_t pp = bc_h2(PJ);                                                \
        float a0 = (float)pp[0];                                            \
        float a1 = (float)pp[1];                                            \
        PJ = LDP((TTT) + 2);            /* 2-steps-ahead prefetch */        \
        uint2 hA = ((const uint2*)h_sh)[hj];   /* lane j: pairs 2j,2j+1 */  \
        _Pragma("unroll")                                                   \
        for (int j = 0; j < 42; ++j) {                                      \
            unsigned int sx = (unsigned int)__builtin_amdgcn_readlane(      \
                (int)hA.x, j);                                              \
            unsigned int sy = (unsigned int)__builtin_amdgcn_readlane(      \
                (int)hA.y, j);                                              \
            a0 = dot2f(bc_h2(w0[2*j+0]), bc_h2(sx), a0);                    \
            a0 = dot2f(bc_h2(w0[2*j+1]), bc_h2(sy), a0);                    \
            a1 = dot2f(bc_h2(w1[2*j+0]), bc_h2(sx), a1);                    \
            a1 = dot2f(bc_h2(w1[2*j+1]), bc_h2(sy), a1);                    \
        }                                                                   \
        float act0 = sigm_f(a0);                 /* i (low) or f (high) */  \
        float xs = low ? (a1 + a1) : a1;                                    \
        float ss = sigm_f(xs);                                              \
        float act1 = low ? (ss + ss - 1.0f) : ss; /* g=tanh or o=sigm */    \
        if (active && !low) gsh[L - H] = make_float2(act0, act1);           \
        bar_lds();                                                          \
        if (tid < H) {                                                      \
            float2 fo = gsh[tid];                 /* (fg, og) */            \
            c = fo.x * c + act0 * act1;           /* own ig, gg */          \
            float hval = fo.y * tanh_f(c);                                  \
            hcat[((size_t)b * TT + t) * (2 * H) + (size_t)d * H + tid] = hval; \
            ((__half*)h_sh)[tid] = __float2half(hval);                      \
        }                                                                   \
        bar_lds();                                                          \
    }

    for (int base = 0; base < TT; base += 2) {
        STEP(base,     p0)
        STEP(base + 1, p1)
    }
    #undef STEP
    #undef LDP
}

// ---------------------------------------------------------------------------
// lin_gemm: out[m][n] = relu?(sum_k hcat[m][k]*W[n][k] + bl[n]) + res[m][n]
// ---------------------------------------------------------------------------
__global__ __launch_bounds__(256) void lin_gemm(
    const float* __restrict__ A,     // [M_TOT][2H]
    const float* __restrict__ W,     // [H][2H]
    const float* __restrict__ bl,    // [H]
    const float* __restrict__ res,   // [M_TOT][H]
    float* __restrict__ out,         // [M_TOT][H]
    int relu)
{
    const int BM = 64, BN = 64, BK = 16;
    const int K = 2 * H;
    int m0 = blockIdx.x * BM;
    int n0 = blockIdx.y * BN;
    __shared__ float As[BK][BM + 1];
    __shared__ float Bs[BK][BN + 1];
    int tid = threadIdx.x;
    int tx = tid & 15, ty = tid >> 4;
    float acc[4][4] = {};

    for (int k0 = 0; k0 < K; k0 += BK) {
        #pragma unroll
        for (int l = 0; l < (BM * BK) / 256; ++l) {
            int e = tid + l * 256;
            int mm = e / BK, kk = e % BK;
            int k = k0 + kk;
            As[kk][mm] = (k < K) ? A[(size_t)(m0 + mm) * K + k] : 0.f;
        }
        #pragma unroll
        for (int l = 0; l < (BN * BK) / 256; ++l) {
            int e = tid + l * 256;
            int nn = e / BK, kk = e % BK;
            int n = n0 + nn, k = k0 + kk;
            Bs[kk][nn] = (k < K && n < H) ? W[(size_t)n * K + k] : 0.f;
        }
        __syncthreads();
        #pragma unroll
        for (int kk = 0; kk < BK; ++kk) {
            float a4[4], b4[4];
            #pragma unroll
            for (int i = 0; i < 4; ++i) a4[i] = As[kk][ty + 16 * i];
            #pragma unroll
            for (int j = 0; j < 4; ++j) b4[j] = Bs[kk][tx + 16 * j];
            #pragma unroll
            for (int i = 0; i < 4; ++i)
                #pragma unroll
                for (int j = 0; j < 4; ++j) acc[i][j] += a4[i] * b4[j];
        }
        __syncthreads();
    }

    #pragma unroll
    for (int i = 0; i < 4; ++i) {
        int m = m0 + ty + 16 * i;
        #pragma unroll
        for (int j = 0; j < 4; ++j) {
            int n = n0 + tx + 16 * j;
            if (n < H) {
                float v = acc[i][j] + bl[n];
                if (relu) v = fmaxf(v, 0.f);
                v += res[(size_t)m * H + n];
                out[(size_t)m * H + n] = v;
            }
        }
    }
}

extern "C" void kernel_launch(void* const* d_in, const int* in_sizes, int n_in,
                              void* d_out, int out_size, void* d_ws, size_t ws_size,
                              hipStream_t stream) {
    const float* x = (const float*)d_in[0];

    char* ws = (char*)d_ws;
    __half* pre2 = (__half*)ws;          // 2*32000*322 uints = 82.4 MB
    float* hcat = (float*)(ws + (size_t)2 * M_TOT * H2 * sizeof(unsigned int));
    float* bufA = hcat + (size_t)M_TOT * 2 * H;
    float* bufB = bufA + (size_t)M_TOT * H;

    const float* cur = x;
    float* outs[3] = {bufA, bufB, (float*)d_out};

    for (int l = 0; l < 3; ++l) {
        const float* const* p = (const float* const*)(d_in + 1 + 10 * l);
        dim3 g1(M_TOT / 64, 21);
        pre_gemm<<<g1, 256, 0, stream>>>(cur, p[0], p[4], p[2], p[3], p[6], p[7], pre2);
        lstm_scan<<<dim3(32, 2), 384, 0, stream>>>((const unsigned int*)pre2,
                                                   p[1], p[5], hcat);
        dim3 g2(M_TOT / 64, 3);
        lin_gemm<<<g2, 256, 0, stream>>>(hcat, p[8], p[9], cur, outs[l], (l < 2) ? 1 : 0);
        cur = outs[l];
    }
}